// Round 12
// baseline (58.130 us; speedup 1.0000x reference)
//
#include <hip/hip_runtime.h>
#include <hip/hip_bf16.h>
#include <math.h>

// Problem constants: B=2, L=512, D=1024, H=16, DH=64. N = B*L = 1024.
// 5 dispatches: cvtT(+gate-scan blocks 0..31) -> gemmQKC(3-deep pipeline,
// +dS0 in z=1 epilogue) -> out0_ds1(512t) -> out1_k(512t) -> gemmP(512t).

typedef unsigned short ushort_t;
typedef __attribute__((ext_vector_type(8))) short bf16x8;
typedef __attribute__((ext_vector_type(4))) float f32x4;

__device__ __forceinline__ float sigmoidf_(float z) { return 1.f / (1.f + expf(-z)); }

__device__ __forceinline__ ushort_t f2bf(float f) {
    __hip_bfloat16 h = __float2bfloat16(f);
    return *reinterpret_cast<ushort_t*>(&h);
}

__device__ __forceinline__ float bf2f(ushort_t u) {
    union { unsigned int i; float f; } v;
    v.i = ((unsigned int)u) << 16;
    return v.f;
}

__device__ __forceinline__ void gl16(const void* g, void* l) {
    __builtin_amdgcn_global_load_lds(
        (const __attribute__((address_space(1))) unsigned int*)g,
        (__attribute__((address_space(3))) unsigned int*)l, 16, 0, 0);
}

// ---------------------------------------------------------------------------
// cvtT: blocks 0..31: gate prefix-scan per (b,h) -> gc.
//       blocks 32..1055: transpose-convert 4 weights fp32[K][N] -> bf16[N][K].
//       blocks 1056..1567: convert x fp32 -> bf16.
// ---------------------------------------------------------------------------
__global__ __launch_bounds__(256) void cvtT(const float* __restrict__ xs,
                                            const float* __restrict__ w0, const float* __restrict__ w1,
                                            const float* __restrict__ w2, const float* __restrict__ w3,
                                            const float* __restrict__ gwwp,
                                            const float* __restrict__ gwbp,
                                            ushort_t* __restrict__ xd,
                                            ushort_t* __restrict__ t0, ushort_t* __restrict__ t1,
                                            ushort_t* __restrict__ t2, ushort_t* __restrict__ t3,
                                            float* __restrict__ gc_out) {
    const int blk = blockIdx.x;
    const int tid = threadIdx.x;

    if (blk < 32) {
        // ---- gate scan for (b,h) = blk ----
        const int bh = blk;
        const int b = bh >> 4, h = bh & 15;
        const int w = tid >> 6, lane = tid & 63;
        __shared__ float gwl[64];
        __shared__ float ctot[8];
        if (tid < 64) gwl[tid] = gwwp[tid];
        __syncthreads();
        const float gwbv = gwbp[0];
        float psv[2];
#pragma unroll
        for (int p = 0; p < 2; ++p) {
            const int c = p * 4 + w;
            const int t = c * 64 + lane;
            const float* xr = xs + (size_t)(b * 512 + t) * 1024 + h * 64;
            float dg = 0.f;
#pragma unroll
            for (int d = 0; d < 64; d += 4) {
                float4 xv = *reinterpret_cast<const float4*>(xr + d);
                dg += xv.x * gwl[d] + xv.y * gwl[d + 1] + xv.z * gwl[d + 2] + xv.w * gwl[d + 3];
            }
            const float g = sigmoidf_(dg + gwbv);
            float ps = logf(fmaxf(g, 1e-6f));
#pragma unroll
            for (int off = 1; off < 64; off <<= 1) {
                float v = __shfl_up(ps, off, 64);
                if (lane >= off) ps += v;
            }
            psv[p] = ps;
            if (lane == 63) ctot[c] = ps;
        }
        __syncthreads();
#pragma unroll
        for (int p = 0; p < 2; ++p) {
            const int c = p * 4 + w;
            float coff = 0.f;
            for (int cc = 0; cc < c; ++cc) coff += ctot[cc];
            const float lsum = coff + psv[p];
            gc_out[bh * 512 + c * 64 + lane] =
                expf(fminf(fmaxf(lsum, -30.f), 30.f)) + 1e-6f;
        }
        return;
    }

    const int wblk = blk - 32;
    if (wblk >= 1024) {
        const int off = ((wblk - 1024) * 256 + tid) * 8;
        float4 a = *reinterpret_cast<const float4*>(xs + off);
        float4 b = *reinterpret_cast<const float4*>(xs + off + 4);
        union { uint4 v; ushort_t u[8]; } pk;
        pk.u[0] = f2bf(a.x); pk.u[1] = f2bf(a.y); pk.u[2] = f2bf(a.z); pk.u[3] = f2bf(a.w);
        pk.u[4] = f2bf(b.x); pk.u[5] = f2bf(b.y); pk.u[6] = f2bf(b.z); pk.u[7] = f2bf(b.w);
        *reinterpret_cast<uint4*>(xd + off) = pk.v;
        return;
    }
    const int wi = wblk >> 8;
    const float* W = wi == 0 ? w0 : wi == 1 ? w1 : wi == 2 ? w2 : w3;
    ushort_t* WT = wi == 0 ? t0 : wi == 1 ? t1 : wi == 2 ? t2 : t3;
    const int tile = wblk & 255;
    const int k0 = (tile >> 4) * 64, n0 = (tile & 15) * 64;
    __shared__ ushort_t T[64][72];
#pragma unroll
    for (int it = 0; it < 4; ++it) {
        const int idx = tid + it * 256;
        const int r = idx >> 4;
        const int c4 = (idx & 15) * 4;
        float4 v = *reinterpret_cast<const float4*>(W + (size_t)(k0 + r) * 1024 + n0 + c4);
        T[r][c4 + 0] = f2bf(v.x); T[r][c4 + 1] = f2bf(v.y);
        T[r][c4 + 2] = f2bf(v.z); T[r][c4 + 3] = f2bf(v.w);
    }
    __syncthreads();
    const int n = tid >> 2;
    const int kq = (tid & 3) * 16;
    union { uint4 v[2]; ushort_t u[16]; } pk;
#pragma unroll
    for (int j = 0; j < 16; ++j) pk.u[j] = T[kq + j][n];
    *reinterpret_cast<uint4*>(WT + (size_t)(n0 + n) * 1024 + k0 + kq) = pk.v[0];
    *reinterpret_cast<uint4*>(WT + (size_t)(n0 + n) * 1024 + k0 + kq + 8) = pk.v[1];
}

// ---------------------------------------------------------------------------
// gemmQKC: z-split GEMM (768 blocks), 3-deep counted-vmcnt pipeline.
// z=0: Q (qb + leaky q2b). z=1: K (kb) + a/dS0 epilogue (K-tile in regs,
// Gc precomputed by cvtT). z=2: K2.
// ---------------------------------------------------------------------------
__global__ __launch_bounds__(256) void gemmQKC(const ushort_t* __restrict__ Ab,
                                               const ushort_t* __restrict__ WqT,
                                               const ushort_t* __restrict__ WkT,
                                               const ushort_t* __restrict__ WcT,
                                               const float* __restrict__ bq_,
                                               const float* __restrict__ bk_,
                                               const float* __restrict__ bc_,
                                               const float* __restrict__ x,
                                               const float* __restrict__ sww,
                                               const float* __restrict__ swb,
                                               const float* __restrict__ gc,
                                               ushort_t* __restrict__ qb,
                                               ushort_t* __restrict__ q2b,
                                               ushort_t* __restrict__ kb,
                                               ushort_t* __restrict__ k2q,
                                               float* __restrict__ ab_out,
                                               float* __restrict__ dS0) {
    const int sel = blockIdx.z;
    const ushort_t* WT = sel == 0 ? WqT : sel == 1 ? WkT : WcT;
    const float* bias = sel == 0 ? bq_ : sel == 1 ? bk_ : bc_;
    const int m0 = blockIdx.y * 64, n0 = blockIdx.x * 64;

    __shared__ __align__(16) char smem[49152];   // As[3] @0, Bs[3] @24576

    const int tid = threadIdx.x;
    const int w = tid >> 6, lane = tid & 63;
    const int l15 = lane & 15, lq = lane >> 4;

    f32x4 acc[4];
#pragma unroll
    for (int i = 0; i < 4; ++i) acc[i] = (f32x4){0.f, 0.f, 0.f, 0.f};

    auto stage = [&](int buf, int k0) {
        char* As = smem + buf * 8192;
        char* Bs = smem + 24576 + buf * 8192;
#pragma unroll
        for (int is = 0; is < 2; ++is) {
            const int p = tid * 16 + is * 4096;
            const int row = p >> 7;
            const int scb = (p & 127) ^ ((row & 7) << 4);
            gl16((const char*)Ab + (((size_t)(m0 + row)) << 11) + (k0 << 1) + scb,
                 As + is * 4096 + w * 1024);
            gl16((const char*)WT + (((size_t)(n0 + row)) << 11) + (k0 << 1) + scb,
                 Bs + is * 4096 + w * 1024);
        }
    };

    stage(0, 0);
    stage(1, 64);
#pragma unroll
    for (int it = 0; it < 16; ++it) {
        const int k0 = it * 64;
        const int cur = it % 3;
        if (it < 14) stage((it + 2) % 3, k0 + 128);
        if (it < 14)      asm volatile("s_waitcnt vmcnt(8)" ::: "memory");
        else if (it == 14) asm volatile("s_waitcnt vmcnt(4)" ::: "memory");
        else               asm volatile("s_waitcnt vmcnt(0)" ::: "memory");
        __builtin_amdgcn_sched_barrier(0);
        __builtin_amdgcn_s_barrier();
        const char* As = smem + cur * 8192;
        const char* Bs = smem + 24576 + cur * 8192;
#pragma unroll
        for (int kk = 0; kk < 64; kk += 32) {
            const int cb = (kk + 8 * lq) * 2;
            const int ra = 16 * w + l15;
            bf16x8 a = *reinterpret_cast<const bf16x8*>(As + ra * 128 + (cb ^ ((ra & 7) << 4)));
#pragma unroll
            for (int nt = 0; nt < 4; ++nt) {
                const int rb = 16 * nt + l15;
                bf16x8 b = *reinterpret_cast<const bf16x8*>(Bs + rb * 128 + (cb ^ ((rb & 7) << 4)));
                acc[nt] = __builtin_amdgcn_mfma_f32_16x16x32_bf16(a, b, acc[nt], 0, 0, 0);
            }
        }
        asm volatile("s_waitcnt lgkmcnt(0)" ::: "memory");
        __builtin_amdgcn_sched_barrier(0);
        __builtin_amdgcn_s_barrier();
    }

    // fold bias into acc, write per-z outputs
#pragma unroll
    for (int nt = 0; nt < 4; ++nt) {
        const int col = n0 + 16 * nt + l15;
        const float bcol = bias[col];
#pragma unroll
        for (int r = 0; r < 4; ++r) {
            acc[nt][r] += bcol;
            const int row = m0 + 16 * w + 4 * lq + r;
            const size_t o = (size_t)row * 1024 + col;
            const float v = acc[nt][r];
            if (sel == 0) {
                qb[o] = f2bf(v);
                q2b[o] = f2bf((v < 0.f ? v : 0.02f * v) * 0.125f);
            } else if (sel == 1) {
                kb[o] = f2bf(v);
            } else {
                k2q[o] = f2bf(sigmoidf_(v * 6.25e-4f));
            }
        }
    }

    if (sel != 1) return;

    // ---- z=1 epilogue: a = silu(K.sw)/Gc + dS0 (K-tile is `acc`) ----
    typedef ushort_t row72[72];
    row72* KT = (row72*)smem;              // 9216 B  [d][tau]
    row72* VT = (row72*)(smem + 9216);     // 9216 B  [e][tau]
    float* abl = (float*)(smem + 18432);   // 64
    float* dkl = (float*)(smem + 18688);   // 64
    const int b = blockIdx.y >> 3, j = blockIdx.y & 7;
    const int h = blockIdx.x;
    const int bh = b * 16 + h;
    const size_t xbase = (size_t)(b * 512) * 1024 + h * 64;

    {
        const float s0 = sww[l15], s1 = sww[16 + l15], s2 = sww[32 + l15], s3 = sww[48 + l15];
#pragma unroll
        for (int r = 0; r < 4; ++r) {
            float p = acc[0][r] * s0 + acc[1][r] * s1 + acc[2][r] * s2 + acc[3][r] * s3;
            p += __shfl_xor(p, 1, 64);
            p += __shfl_xor(p, 2, 64);
            p += __shfl_xor(p, 4, 64);
            p += __shfl_xor(p, 8, 64);
            if (l15 == 0) dkl[16 * w + 4 * lq + r] = p;
        }
    }
    __syncthreads();
    if (tid < 64) {
        const float Gc = gc[bh * 512 + j * 64 + tid];
        const float z = dkl[tid] + swb[0];
        const float a = z * sigmoidf_(z) / Gc;
        abl[tid] = a;
        ab_out[bh * 512 + j * 64 + tid] = a;
    }
    __syncthreads();

#pragma unroll
    for (int nt = 0; nt < 4; ++nt)
#pragma unroll
        for (int r = 0; r < 4; ++r)
            KT[16 * nt + l15][16 * w + 4 * lq + r] = f2bf(acc[nt][r]);
#pragma unroll
    for (int it = 0; it < 4; ++it) {
        const int idx = tid + it * 256;
        const int rr = idx >> 4;
        const int c4 = (idx & 15) << 2;
        float4 xv = *reinterpret_cast<const float4*>(x + xbase + (size_t)(j * 64 + rr) * 1024 + c4);
        const float a = abl[rr];
        VT[c4 + 0][rr] = f2bf(a * xv.x); VT[c4 + 1][rr] = f2bf(a * xv.y);
        VT[c4 + 2][rr] = f2bf(a * xv.z); VT[c4 + 3][rr] = f2bf(a * xv.w);
    }
    __syncthreads();

    f32x4 st[4];
#pragma unroll
    for (int n = 0; n < 4; ++n) st[n] = (f32x4){0.f, 0.f, 0.f, 0.f};
#pragma unroll
    for (int kk = 0; kk < 64; kk += 32) {
        bf16x8 ak = *reinterpret_cast<const bf16x8*>(&KT[16 * w + l15][kk + 8 * lq]);
#pragma unroll
        for (int n = 0; n < 4; ++n) {
            bf16x8 vb = *reinterpret_cast<const bf16x8*>(&VT[16 * n + l15][kk + 8 * lq]);
            st[n] = __builtin_amdgcn_mfma_f32_16x16x32_bf16(ak, vb, st[n], 0, 0, 0);
        }
    }
    float* o = dS0 + (size_t)(bh * 8 + j) * 4096;
#pragma unroll
    for (int n = 0; n < 4; ++n)
#pragma unroll
        for (int r = 0; r < 4; ++r)
            o[(16 * w + 4 * lq + r) * 64 + 16 * n + l15] = st[n][r];
}

// ---------------------------------------------------------------------------
// out0_ds1 (512 threads, 8 waves): GLA output chunk + dS1 + EbT emission.
// wave = (tw = w>>1 : t/d-tile, eh = w&1 : e/c-half). 2 fragments per wave.
// ---------------------------------------------------------------------------
__global__ __launch_bounds__(512) void out0_ds1(const float* __restrict__ x,
                                                const ushort_t* __restrict__ xb,
                                                const ushort_t* __restrict__ Qb,
                                                const ushort_t* __restrict__ Kb,
                                                const ushort_t* __restrict__ K2b,
                                                const float* __restrict__ gc,
                                                const float* __restrict__ ab,
                                                const float* __restrict__ dS0,
                                                float* __restrict__ O1out,
                                                float* __restrict__ dS1,
                                                ushort_t* __restrict__ EbT) {
    const int rt = blockIdx.x, bh = blockIdx.y;
    const int b = bh >> 4, h = bh & 15;
    const int c0 = rt * 64;
    const int tid = threadIdx.x;
    const int w = tid >> 6, lane = tid & 63;
    const int l15 = lane & 15, lq = lane >> 4;
    const int tw = w >> 1, eh = w & 1;

    __shared__ __align__(16) char Qs[8192];
    __shared__ __align__(16) char Ks[8192];
    __shared__ ushort_t VT[64][72];
    __shared__ ushort_t K2T[64][72];
    __shared__ ushort_t ET[64][72];
    __shared__ ushort_t Ps[64][72];
    __shared__ ushort_t SBt[64][72];
    __shared__ float av[64], gcv[64];

    const size_t base = (size_t)(b * 512) * 1024 + h * 64;
    const size_t rowB = (size_t)(b * 512 + c0) * 2048 + h * 128;

    {
        const int p = tid * 16;
        const int row = p >> 7;
        const int scb = (p & 127) ^ ((row & 7) << 4);
        gl16((const char*)Qb + rowB + (size_t)row * 2048 + scb, Qs + w * 1024);
        gl16((const char*)Kb + rowB + (size_t)row * 2048 + scb, Ks + w * 1024);
    }
#pragma unroll
    for (int it = 0; it < 2; ++it) {
        const int idx = tid + it * 512;
        const int rr = idx >> 4;
        const int c4 = (idx & 15) << 2;
        const int tau = c0 + rr;
        ushort4 xv = *reinterpret_cast<const ushort4*>(xb + base + (size_t)tau * 1024 + c4);
        VT[c4 + 0][rr] = xv.x; VT[c4 + 1][rr] = xv.y;
        VT[c4 + 2][rr] = xv.z; VT[c4 + 3][rr] = xv.w;
        ushort4 cv = *reinterpret_cast<const ushort4*>(K2b + base + (size_t)tau * 1024 + c4);
        K2T[c4 + 0][rr] = cv.x; K2T[c4 + 1][rr] = cv.y;
        K2T[c4 + 2][rr] = cv.z; K2T[c4 + 3][rr] = cv.w;
    }
    if (tid < 64) av[tid] = ab[bh * 512 + c0 + tid];
    else if (tid < 128) gcv[tid - 64] = gc[bh * 512 + c0 + tid - 64];

#pragma unroll
    for (int ii = 0; ii < 2; ++ii) {
        const int flat = tid * 8 + ii * 4;
        float4 s = {0.f, 0.f, 0.f, 0.f};
        for (int jj = 0; jj < rt; ++jj) {
            float4 v = *reinterpret_cast<const float4*>(dS0 + (size_t)(bh * 8 + jj) * 4096 + flat);
            s.x += v.x; s.y += v.y; s.z += v.z; s.w += v.w;
        }
        const int d = flat >> 6, e = flat & 63;
        SBt[e + 0][d] = f2bf(s.x); SBt[e + 1][d] = f2bf(s.y);
        SBt[e + 2][d] = f2bf(s.z); SBt[e + 3][d] = f2bf(s.w);
    }
    __syncthreads();

    const int ra = 16 * tw + l15;
    f32x4 sc[2];
    sc[0] = (f32x4){0.f, 0.f, 0.f, 0.f};
    sc[1] = (f32x4){0.f, 0.f, 0.f, 0.f};
#pragma unroll
    for (int kk = 0; kk < 64; kk += 32) {
        const int cb = (kk + 8 * lq) * 2;
        bf16x8 aq = *reinterpret_cast<const bf16x8*>(Qs + ra * 128 + (cb ^ ((ra & 7) << 4)));
#pragma unroll
        for (int i = 0; i < 2; ++i) {
            const int rb = 16 * (2 * eh + i) + l15;
            bf16x8 bb = *reinterpret_cast<const bf16x8*>(Ks + rb * 128 + (cb ^ ((rb & 7) << 4)));
            sc[i] = __builtin_amdgcn_mfma_f32_16x16x32_bf16(aq, bb, sc[i], 0, 0, 0);
        }
    }
#pragma unroll
    for (int i = 0; i < 2; ++i) {
        const int cl = 16 * (2 * eh + i) + l15;
#pragma unroll
        for (int r = 0; r < 4; ++r) {
            const int tl = 16 * tw + 4 * lq + r;
            Ps[tl][cl] = f2bf(cl <= tl ? sc[i][r] * av[cl] : 0.f);
        }
    }
    __syncthreads();

    f32x4 oc[2];
    oc[0] = (f32x4){0.f, 0.f, 0.f, 0.f};
    oc[1] = (f32x4){0.f, 0.f, 0.f, 0.f};
#pragma unroll
    for (int kk = 0; kk < 64; kk += 32) {
        const int cb = (kk + 8 * lq) * 2;
        bf16x8 aq = *reinterpret_cast<const bf16x8*>(Qs + ra * 128 + (cb ^ ((ra & 7) << 4)));
        bf16x8 ap = *reinterpret_cast<const bf16x8*>(&Ps[16 * tw + l15][kk + 8 * lq]);
#pragma unroll
        for (int i = 0; i < 2; ++i) {
            const int nb = 16 * (2 * eh + i) + l15;
            bf16x8 sb = *reinterpret_cast<const bf16x8*>(&SBt[nb][kk + 8 * lq]);
            oc[i] = __builtin_amdgcn_mfma_f32_16x16x32_bf16(aq, sb, oc[i], 0, 0, 0);
            bf16x8 vb = *reinterpret_cast<const bf16x8*>(&VT[nb][kk + 8 * lq]);
            oc[i] = __builtin_amdgcn_mfma_f32_16x16x32_bf16(ap, vb, oc[i], 0, 0, 0);
        }
    }

#pragma unroll
    for (int i = 0; i < 2; ++i) {
        const int e = 16 * (2 * eh + i) + l15;
#pragma unroll
        for (int r = 0; r < 4; ++r) {
            const int tl = 16 * tw + 4 * lq + r;
            const int tau = c0 + tl;
            const float val = gcv[tl] * oc[i][r];
            O1out[base + (size_t)tau * 1024 + e] = val;
            float ev = 0.f;
            if (tau <= 510) ev = x[base + (size_t)(tau + 1) * 1024 + e] - val;
            ET[e][tl] = f2bf(ev);
        }
    }
    __syncthreads();

    {
        const int e = tid >> 3;
        const int tq = (tid & 7) * 8;
        uint4 v0 = *reinterpret_cast<const uint4*>(&ET[e][tq]);
        *reinterpret_cast<uint4*>(EbT + (size_t)(bh * 64 + e) * 512 + c0 + tq) = v0;
    }

    f32x4 st[2];
    st[0] = (f32x4){0.f, 0.f, 0.f, 0.f};
    st[1] = (f32x4){0.f, 0.f, 0.f, 0.f};
#pragma unroll
    for (int kk = 0; kk < 64; kk += 32) {
        bf16x8 ak = *reinterpret_cast<const bf16x8*>(&K2T[16 * tw + l15][kk + 8 * lq]);
#pragma unroll
        for (int i = 0; i < 2; ++i) {
            bf16x8 eb = *reinterpret_cast<const bf16x8*>(&ET[16 * (2 * eh + i) + l15][kk + 8 * lq]);
            st[i] = __builtin_amdgcn_mfma_f32_16x16x32_bf16(ak, eb, st[i], 0, 0, 0);
        }
    }
    float* o = dS1 + (size_t)(bh * 8 + rt) * 4096;
#pragma unroll
    for (int i = 0; i < 2; ++i)
#pragma unroll
        for (int r = 0; r < 4; ++r)
            o[(16 * tw + 4 * lq + r) * 64 + 16 * (2 * eh + i) + l15] = st[i][r];
}

// ---------------------------------------------------------------------------
// out1 (512 threads): MA-branch output + final y in bf16.
// ---------------------------------------------------------------------------
__global__ __launch_bounds__(512) void out1_k(const ushort_t* __restrict__ Q2b,
                                              const ushort_t* __restrict__ K2b,
                                              const ushort_t* __restrict__ EbT,
                                              const float* __restrict__ O1,
                                              const float* __restrict__ dS1,
                                              ushort_t* __restrict__ yout) {
    const int rt = blockIdx.x, bh = blockIdx.y;
    const int b = bh >> 4, h = bh & 15;
    const int c0 = rt * 64;
    const int tid = threadIdx.x;
    const int w = tid >> 6, lane = tid & 63;
    const int l15 = lane & 15, lq = lane >> 4;
    const int tw = w >> 1, eh = w & 1;

    __shared__ __align__(16) char Q2s[8192];
    __shared__ __align__(16) char K2s[8192];
    __shared__ __align__(16) char ETs[8192];
    __shared__ ushort_t Ps[64][72];
    __shared__ ushort_t SBt[64][72];

    const size_t base = (size_t)(b * 512) * 1024 + h * 64;
    const size_t rowB = (size_t)(b * 512 + c0) * 2048 + h * 128;

    {
        const int p = tid * 16;
        const int row = p >> 7;
        const int scb = (p & 127) ^ ((row & 7) << 4);
        gl16((const char*)Q2b + rowB + (size_t)row * 2048 + scb, Q2s + w * 1024);
        gl16((const char*)K2b + rowB + (size_t)row * 2048 + scb, K2s + w * 1024);
        gl16((const char*)EbT + (size_t)(bh * 64 + row) * 1024 + c0 * 2 + scb, ETs + w * 1024);
    }
#pragma unroll
    for (int ii = 0; ii < 2; ++ii) {
        const int flat = tid * 8 + ii * 4;
        float4 s = {0.f, 0.f, 0.f, 0.f};
        for (int jj = 0; jj < rt; ++jj) {
            float4 v = *reinterpret_cast<const float4*>(dS1 + (size_t)(bh * 8 + jj) * 4096 + flat);
            s.x += v.x; s.y += v.y; s.z += v.z; s.w += v.w;
        }
        const int d = flat >> 6, e = flat & 63;
        SBt[e + 0][d] = f2bf(s.x); SBt[e + 1][d] = f2bf(s.y);
        SBt[e + 2][d] = f2bf(s.z); SBt[e + 3][d] = f2bf(s.w);
    }
    __syncthreads();

    const int ra = 16 * tw + l15;
    f32x4 sc[2];
    sc[0] = (f32x4){0.f, 0.f, 0.f, 0.f};
    sc[1] = (f32x4){0.f, 0.f, 0.f, 0.f};
#pragma unroll
    for (int kk = 0; kk < 64; kk += 32) {
        const int cb = (kk + 8 * lq) * 2;
        bf16x8 aq = *reinterpret_cast<const bf16x8*>(Q2s + ra * 128 + (cb ^ ((ra & 7) << 4)));
#pragma unroll
        for (int i = 0; i < 2; ++i) {
            const int rb = 16 * (2 * eh + i) + l15;
            bf16x8 bb = *reinterpret_cast<const bf16x8*>(K2s + rb * 128 + (cb ^ ((rb & 7) << 4)));
            sc[i] = __builtin_amdgcn_mfma_f32_16x16x32_bf16(aq, bb, sc[i], 0, 0, 0);
        }
    }
#pragma unroll
    for (int i = 0; i < 2; ++i) {
        const int cl = 16 * (2 * eh + i) + l15;
#pragma unroll
        for (int r = 0; r < 4; ++r) {
            const int tl = 16 * tw + 4 * lq + r;
            Ps[tl][cl] = f2bf(cl <= tl ? sc[i][r] : 0.f);
        }
    }
    __syncthreads();

    f32x4 oc[2];
    oc[0] = (f32x4){0.f, 0.f, 0.f, 0.f};
    oc[1] = (f32x4){0.f, 0.f, 0.f, 0.f};
#pragma unroll
    for (int kk = 0; kk < 64; kk += 32) {
        const int cb = (kk + 8 * lq) * 2;
        bf16x8 aq = *reinterpret_cast<const bf16x8*>(Q2s + ra * 128 + (cb ^ ((ra & 7) << 4)));
        bf16x8 ap = *reinterpret_cast<const bf16x8*>(&Ps[16 * tw + l15][kk + 8 * lq]);
#pragma unroll
        for (int i = 0; i < 2; ++i) {
            const int rb = 16 * (2 * eh + i) + l15;
            bf16x8 sb = *reinterpret_cast<const bf16x8*>(&SBt[rb][kk + 8 * lq]);
            oc[i] = __builtin_amdgcn_mfma_f32_16x16x32_bf16(aq, sb, oc[i], 0, 0, 0);
            bf16x8 eb = *reinterpret_cast<const bf16x8*>(ETs + rb * 128 + (cb ^ ((rb & 7) << 4)));
            oc[i] = __builtin_amdgcn_mfma_f32_16x16x32_bf16(ap, eb, oc[i], 0, 0, 0);
        }
    }

#pragma unroll
    for (int i = 0; i < 2; ++i) {
        const int e = 16 * (2 * eh + i) + l15;
#pragma unroll
        for (int r = 0; r < 4; ++r) {
            const int tp = c0 + 16 * tw + 4 * lq + r;
            if (tp <= 510) {
                yout[(size_t)(b * 512 + tp + 1) * 1024 + h * 64 + e] =
                    f2bf(O1[base + (size_t)(tp + 1) * 1024 + e] + oc[i][r]);
            }
        }
    }
    if (rt == 0 && tid < 64)
        yout[(size_t)(b * 512) * 1024 + h * 64 + tid] = f2bf(O1[base + tid]);
}

// ---------------------------------------------------------------------------
// gemmP (512 threads): final projection, fp32 out, 3-deep counted-vmcnt.
// ---------------------------------------------------------------------------
__global__ __launch_bounds__(512) void gemmP(const ushort_t* __restrict__ Ab,
                                             const ushort_t* __restrict__ WT,
                                             const float* __restrict__ bias,
                                             float* __restrict__ Out) {
    const int m0 = blockIdx.y * 64, n0 = blockIdx.x * 64;
    __shared__ __align__(16) char smem[49152];   // As[3] @0, Bs[3] @24576

    const int tid = threadIdx.x;
    const int w = tid >> 6, lane = tid & 63;
    const int l15 = lane & 15, lq = lane >> 4;
    const int mw = w >> 1, nh = w & 1;

    f32x4 acc[2];
    acc[0] = (f32x4){0.f, 0.f, 0.f, 0.f};
    acc[1] = (f32x4){0.f, 0.f, 0.f, 0.f};

    auto stage = [&](int buf, int k0) {
        const int p = tid * 16;
        const int row = p >> 7;
        const int scb = (p & 127) ^ ((row & 7) << 4);
        gl16((const char*)Ab + (((size_t)(m0 + row)) << 11) + (k0 << 1) + scb,
             smem + buf * 8192 + w * 1024);
        gl16((const char*)WT + (((size_t)(n0 + row)) << 11) + (k0 << 1) + scb,
             smem + 24576 + buf * 8192 + w * 1024);
    };

    stage(0, 0);
    stage(1, 64);
#pragma unroll
    for (int it = 0; it < 16; ++it) {
        const int k0 = it * 64;
        const int cur = it % 3;
        if (it < 14) stage((it + 2) % 3, k0 + 128);
        if (it < 14)      asm volatile("s_waitcnt vmcnt(4)" ::: "memory");
        else if (it == 14) asm volatile("s_waitcnt vmcnt(2)" ::: "memory");
        else               asm volatile("s_waitcnt vmcnt(0)" ::: "memory");
        __builtin_amdgcn_sched_barrier(0);
        __builtin_amdgcn_s_barrier();
        const char* As = smem + cur * 8192;
        const char* Bs = smem + 24576 + cur * 8192;
#pragma unroll
        for (int kk = 0; kk < 64; kk += 32) {
            const int cb = (kk + 8 * lq) * 2;
            const int ra = 16 * mw + l15;
            bf16x8 a = *reinterpret_cast<const bf16x8*>(As + ra * 128 + (cb ^ ((ra & 7) << 4)));
#pragma unroll
            for (int i = 0; i < 2; ++i) {
                const int rb = 16 * (2 * nh + i) + l15;
                bf16x8 b = *reinterpret_cast<const bf16x8*>(Bs + rb * 128 + (cb ^ ((rb & 7) << 4)));
                acc[i] = __builtin_amdgcn_mfma_f32_16x16x32_bf16(a, b, acc[i], 0, 0, 0);
            }
        }
        asm volatile("s_waitcnt lgkmcnt(0)" ::: "memory");
        __builtin_amdgcn_sched_barrier(0);
        __builtin_amdgcn_s_barrier();
    }
#pragma unroll
    for (int i = 0; i < 2; ++i) {
        const int col = n0 + 16 * (2 * nh + i) + l15;
        const float bcol = bias[col];
#pragma unroll
        for (int r = 0; r < 4; ++r) {
            const int row = m0 + 16 * mw + 4 * lq + r;
            Out[(size_t)row * 1024 + col] = acc[i][r] + bcol;
        }
    }
}

// ---------------------------------------------------------------------------
extern "C" void kernel_launch(void* const* d_in, const int* in_sizes, int n_in,
                              void* d_out, int out_size, void* d_ws, size_t ws_size,
                              hipStream_t stream) {
    const float* x   = (const float*)d_in[0];
    const float* q1w = (const float*)d_in[1];
    const float* q1b = (const float*)d_in[2];
    const float* k1w = (const float*)d_in[3];
    const float* k1b = (const float*)d_in[4];
    const float* k2w = (const float*)d_in[5];
    const float* k2b = (const float*)d_in[6];
    const float* gww = (const float*)d_in[7];
    const float* gwb = (const float*)d_in[8];
    const float* sww = (const float*)d_in[9];
    const float* swb = (const float*)d_in[10];
    const float* cpw = (const float*)d_in[11];
    const float* cpb = (const float*)d_in[12];
    float* out = (float*)d_out;

    float* ws = (float*)d_ws;
    float* O1   = ws;                       // 1M floats
    float* dS0b = ws + 1048576;             // 1M
    float* dS1b = ws + 2097152;             // 1M
    float* gcb  = ws + 3145728;             // 16K
    float* abb  = ws + 3162112;             // 16K
    ushort_t* ub = (ushort_t*)(ws + 3178496);
    ushort_t* xb   = ub;                    // 1M ushorts each
    ushort_t* qb   = ub + 1048576;
    ushort_t* q2b  = ub + 2097152;
    ushort_t* kb   = ub + 3145728;
    ushort_t* k2q  = ub + 4194304;
    ushort_t* EbT  = ub + 5242880;
    ushort_t* wqT  = ub + 6291456;
    ushort_t* wkT  = ub + 7340032;
    ushort_t* wcT  = ub + 8388608;
    ushort_t* wpT  = ub + 9437184;
    ushort_t* ytb  = ub + 10485760;
    // end: ~35 MB of d_ws

    cvtT<<<1568, 256, 0, stream>>>(x, q1w, k1w, k2w, cpw, gww, gwb,
                                   xb, wqT, wkT, wcT, wpT, gcb);
    gemmQKC<<<dim3(16, 16, 3), 256, 0, stream>>>(xb, wqT, wkT, wcT, q1b, k1b, k2b,
                                                 x, sww, swb, gcb,
                                                 qb, q2b, kb, k2q, abb, dS0b);
    out0_ds1<<<dim3(8, 32), 512, 0, stream>>>(x, xb, qb, kb, k2q, gcb, abb, dS0b,
                                              O1, dS1b, EbT);
    out1_k<<<dim3(8, 32), 512, 0, stream>>>(q2b, k2q, EbT, O1, dS1b, ytb);
    gemmP<<<dim3(16, 16), 512, 0, stream>>>(ytb, wpT, cpb, out);
}

// Round 13
// 57.257 us; speedup vs baseline: 1.0152x; 1.0152x over previous
//
#include <hip/hip_runtime.h>
#include <hip/hip_bf16.h>
#include <math.h>

// Problem constants: B=2, L=512, D=1024, H=16, DH=64. N = B*L = 1024.
// 5 dispatches: cvtT(+gate-scan blocks 0..31) -> gemmQKC(512t, 3-deep pipeline,
// +dS0 in z=1 epilogue) -> out0_ds1(512t) -> out1_k(512t) -> gemmP(512t).

typedef unsigned short ushort_t;
typedef __attribute__((ext_vector_type(8))) short bf16x8;
typedef __attribute__((ext_vector_type(4))) float f32x4;

__device__ __forceinline__ float sigmoidf_(float z) { return 1.f / (1.f + expf(-z)); }

__device__ __forceinline__ ushort_t f2bf(float f) {
    __hip_bfloat16 h = __float2bfloat16(f);
    return *reinterpret_cast<ushort_t*>(&h);
}

__device__ __forceinline__ float bf2f(ushort_t u) {
    union { unsigned int i; float f; } v;
    v.i = ((unsigned int)u) << 16;
    return v.f;
}

__device__ __forceinline__ void gl16(const void* g, void* l) {
    __builtin_amdgcn_global_load_lds(
        (const __attribute__((address_space(1))) unsigned int*)g,
        (__attribute__((address_space(3))) unsigned int*)l, 16, 0, 0);
}

// ---------------------------------------------------------------------------
// cvtT: blocks 0..31: gate prefix-scan per (b,h) -> gc.
//       blocks 32..1055: transpose-convert 4 weights fp32[K][N] -> bf16[N][K].
//       blocks 1056..1567: convert x fp32 -> bf16.
// ---------------------------------------------------------------------------
__global__ __launch_bounds__(256) void cvtT(const float* __restrict__ xs,
                                            const float* __restrict__ w0, const float* __restrict__ w1,
                                            const float* __restrict__ w2, const float* __restrict__ w3,
                                            const float* __restrict__ gwwp,
                                            const float* __restrict__ gwbp,
                                            ushort_t* __restrict__ xd,
                                            ushort_t* __restrict__ t0, ushort_t* __restrict__ t1,
                                            ushort_t* __restrict__ t2, ushort_t* __restrict__ t3,
                                            float* __restrict__ gc_out) {
    const int blk = blockIdx.x;
    const int tid = threadIdx.x;

    if (blk < 32) {
        const int bh = blk;
        const int b = bh >> 4, h = bh & 15;
        const int w = tid >> 6, lane = tid & 63;
        __shared__ float gwl[64];
        __shared__ float ctot[8];
        if (tid < 64) gwl[tid] = gwwp[tid];
        __syncthreads();
        const float gwbv = gwbp[0];
        float psv[2];
#pragma unroll
        for (int p = 0; p < 2; ++p) {
            const int c = p * 4 + w;
            const int t = c * 64 + lane;
            const float* xr = xs + (size_t)(b * 512 + t) * 1024 + h * 64;
            float dg = 0.f;
#pragma unroll
            for (int d = 0; d < 64; d += 4) {
                float4 xv = *reinterpret_cast<const float4*>(xr + d);
                dg += xv.x * gwl[d] + xv.y * gwl[d + 1] + xv.z * gwl[d + 2] + xv.w * gwl[d + 3];
            }
            const float g = sigmoidf_(dg + gwbv);
            float ps = logf(fmaxf(g, 1e-6f));
#pragma unroll
            for (int off = 1; off < 64; off <<= 1) {
                float v = __shfl_up(ps, off, 64);
                if (lane >= off) ps += v;
            }
            psv[p] = ps;
            if (lane == 63) ctot[c] = ps;
        }
        __syncthreads();
#pragma unroll
        for (int p = 0; p < 2; ++p) {
            const int c = p * 4 + w;
            float coff = 0.f;
            for (int cc = 0; cc < c; ++cc) coff += ctot[cc];
            const float lsum = coff + psv[p];
            gc_out[bh * 512 + c * 64 + lane] =
                expf(fminf(fmaxf(lsum, -30.f), 30.f)) + 1e-6f;
        }
        return;
    }

    const int wblk = blk - 32;
    if (wblk >= 1024) {
        const int off = ((wblk - 1024) * 256 + tid) * 8;
        float4 a = *reinterpret_cast<const float4*>(xs + off);
        float4 b = *reinterpret_cast<const float4*>(xs + off + 4);
        union { uint4 v; ushort_t u[8]; } pk;
        pk.u[0] = f2bf(a.x); pk.u[1] = f2bf(a.y); pk.u[2] = f2bf(a.z); pk.u[3] = f2bf(a.w);
        pk.u[4] = f2bf(b.x); pk.u[5] = f2bf(b.y); pk.u[6] = f2bf(b.z); pk.u[7] = f2bf(b.w);
        *reinterpret_cast<uint4*>(xd + off) = pk.v;
        return;
    }
    const int wi = wblk >> 8;
    const float* W = wi == 0 ? w0 : wi == 1 ? w1 : wi == 2 ? w2 : w3;
    ushort_t* WT = wi == 0 ? t0 : wi == 1 ? t1 : wi == 2 ? t2 : t3;
    const int tile = wblk & 255;
    const int k0 = (tile >> 4) * 64, n0 = (tile & 15) * 64;
    __shared__ ushort_t T[64][72];
#pragma unroll
    for (int it = 0; it < 4; ++it) {
        const int idx = tid + it * 256;
        const int r = idx >> 4;
        const int c4 = (idx & 15) * 4;
        float4 v = *reinterpret_cast<const float4*>(W + (size_t)(k0 + r) * 1024 + n0 + c4);
        T[r][c4 + 0] = f2bf(v.x); T[r][c4 + 1] = f2bf(v.y);
        T[r][c4 + 2] = f2bf(v.z); T[r][c4 + 3] = f2bf(v.w);
    }
    __syncthreads();
    const int n = tid >> 2;
    const int kq = (tid & 3) * 16;
    union { uint4 v[2]; ushort_t u[16]; } pk;
#pragma unroll
    for (int j = 0; j < 16; ++j) pk.u[j] = T[kq + j][n];
    *reinterpret_cast<uint4*>(WT + (size_t)(n0 + n) * 1024 + k0 + kq) = pk.v[0];
    *reinterpret_cast<uint4*>(WT + (size_t)(n0 + n) * 1024 + k0 + kq + 8) = pk.v[1];
}

// ---------------------------------------------------------------------------
// gemmQKC (512 threads, 8 waves): z-split GEMM (768 blocks), 3-deep
// counted-vmcnt pipeline. wave = (mw = w>>1 m-tile, nh = w&1 n-half),
// 2 fragments per wave. z=0: Q (+leaky q2b). z=1: K + a/dS0 epilogue. z=2: K2.
// ---------------------------------------------------------------------------
__global__ __launch_bounds__(512) void gemmQKC(const ushort_t* __restrict__ Ab,
                                               const ushort_t* __restrict__ WqT,
                                               const ushort_t* __restrict__ WkT,
                                               const ushort_t* __restrict__ WcT,
                                               const float* __restrict__ bq_,
                                               const float* __restrict__ bk_,
                                               const float* __restrict__ bc_,
                                               const float* __restrict__ x,
                                               const float* __restrict__ sww,
                                               const float* __restrict__ swb,
                                               const float* __restrict__ gc,
                                               ushort_t* __restrict__ qb,
                                               ushort_t* __restrict__ q2b,
                                               ushort_t* __restrict__ kb,
                                               ushort_t* __restrict__ k2q,
                                               float* __restrict__ ab_out,
                                               float* __restrict__ dS0) {
    const int sel = blockIdx.z;
    const ushort_t* WT = sel == 0 ? WqT : sel == 1 ? WkT : WcT;
    const float* bias = sel == 0 ? bq_ : sel == 1 ? bk_ : bc_;
    const int m0 = blockIdx.y * 64, n0 = blockIdx.x * 64;

    __shared__ __align__(16) char smem[49152];   // As[3] @0, Bs[3] @24576

    const int tid = threadIdx.x;
    const int w = tid >> 6, lane = tid & 63;
    const int l15 = lane & 15, lq = lane >> 4;
    const int mw = w >> 1, nh = w & 1;

    f32x4 acc[2];
    acc[0] = (f32x4){0.f, 0.f, 0.f, 0.f};
    acc[1] = (f32x4){0.f, 0.f, 0.f, 0.f};

    auto stage = [&](int buf, int k0) {
        const int p = tid * 16;                       // 0..8191
        const int row = p >> 7;
        const int scb = (p & 127) ^ ((row & 7) << 4);
        gl16((const char*)Ab + (((size_t)(m0 + row)) << 11) + (k0 << 1) + scb,
             smem + buf * 8192 + w * 1024);
        gl16((const char*)WT + (((size_t)(n0 + row)) << 11) + (k0 << 1) + scb,
             smem + 24576 + buf * 8192 + w * 1024);
    };

    stage(0, 0);
    stage(1, 64);
#pragma unroll
    for (int it = 0; it < 16; ++it) {
        const int k0 = it * 64;
        const int cur = it % 3;
        if (it < 14) stage((it + 2) % 3, k0 + 128);
        if (it < 14)      asm volatile("s_waitcnt vmcnt(4)" ::: "memory");
        else if (it == 14) asm volatile("s_waitcnt vmcnt(2)" ::: "memory");
        else               asm volatile("s_waitcnt vmcnt(0)" ::: "memory");
        __builtin_amdgcn_sched_barrier(0);
        __builtin_amdgcn_s_barrier();
        const char* As = smem + cur * 8192;
        const char* Bs = smem + 24576 + cur * 8192;
#pragma unroll
        for (int kk = 0; kk < 64; kk += 32) {
            const int cb = (kk + 8 * lq) * 2;
            const int ra = 16 * mw + l15;
            bf16x8 a = *reinterpret_cast<const bf16x8*>(As + ra * 128 + (cb ^ ((ra & 7) << 4)));
#pragma unroll
            for (int i = 0; i < 2; ++i) {
                const int rb = 16 * (2 * nh + i) + l15;
                bf16x8 b = *reinterpret_cast<const bf16x8*>(Bs + rb * 128 + (cb ^ ((rb & 7) << 4)));
                acc[i] = __builtin_amdgcn_mfma_f32_16x16x32_bf16(a, b, acc[i], 0, 0, 0);
            }
        }
        asm volatile("s_waitcnt lgkmcnt(0)" ::: "memory");
        __builtin_amdgcn_sched_barrier(0);
        __builtin_amdgcn_s_barrier();
    }

    // fold bias into acc, write per-z outputs
#pragma unroll
    for (int i = 0; i < 2; ++i) {
        const int col = n0 + 16 * (2 * nh + i) + l15;
        const float bcol = bias[col];
#pragma unroll
        for (int r = 0; r < 4; ++r) {
            acc[i][r] += bcol;
            const int row = m0 + 16 * mw + 4 * lq + r;
            const size_t o = (size_t)row * 1024 + col;
            const float v = acc[i][r];
            if (sel == 0) {
                qb[o] = f2bf(v);
                q2b[o] = f2bf((v < 0.f ? v : 0.02f * v) * 0.125f);
            } else if (sel == 1) {
                kb[o] = f2bf(v);
            } else {
                k2q[o] = f2bf(sigmoidf_(v * 6.25e-4f));
            }
        }
    }

    if (sel != 1) return;

    // ---- z=1 epilogue: a = silu(K.sw)/Gc + dS0 (K-tile is `acc`) ----
    typedef ushort_t row72[72];
    row72* KT = (row72*)smem;                      // 9216 B  [d][tau]
    row72* VT = (row72*)(smem + 9216);             // 9216 B  [e][tau]
    float* abl  = (float*)(smem + 18432);          // 64
    float* dkl2 = (float*)(smem + 18688);          // 64 x 2
    const int b = blockIdx.y >> 3, j = blockIdx.y & 7;
    const int h = blockIdx.x;
    const int bh = b * 16 + h;
    const size_t xbase = (size_t)(b * 512) * 1024 + h * 64;

    // per-half partial dk[row] = sum over this wave's 32 cols
    {
        const float s0 = sww[16 * 2 * nh + l15], s1 = sww[16 * (2 * nh + 1) + l15];
#pragma unroll
        for (int r = 0; r < 4; ++r) {
            float p = acc[0][r] * s0 + acc[1][r] * s1;
            p += __shfl_xor(p, 1, 64);
            p += __shfl_xor(p, 2, 64);
            p += __shfl_xor(p, 4, 64);
            p += __shfl_xor(p, 8, 64);
            if (l15 == 0) dkl2[(16 * mw + 4 * lq + r) * 2 + nh] = p;
        }
    }
    __syncthreads();
    if (tid < 64) {
        const float Gc = gc[bh * 512 + j * 64 + tid];
        const float z = dkl2[tid * 2] + dkl2[tid * 2 + 1] + swb[0];
        const float a = z * sigmoidf_(z) / Gc;
        abl[tid] = a;
        ab_out[bh * 512 + j * 64 + tid] = a;
    }
    __syncthreads();

    // KT from registers; VT = (a*x)^T
#pragma unroll
    for (int i = 0; i < 2; ++i)
#pragma unroll
        for (int r = 0; r < 4; ++r)
            KT[16 * (2 * nh + i) + l15][16 * mw + 4 * lq + r] = f2bf(acc[i][r]);
#pragma unroll
    for (int it = 0; it < 2; ++it) {
        const int idx = tid + it * 512;
        const int rr = idx >> 4;
        const int c4 = (idx & 15) << 2;
        float4 xv = *reinterpret_cast<const float4*>(x + xbase + (size_t)(j * 64 + rr) * 1024 + c4);
        const float a = abl[rr];
        VT[c4 + 0][rr] = f2bf(a * xv.x); VT[c4 + 1][rr] = f2bf(a * xv.y);
        VT[c4 + 2][rr] = f2bf(a * xv.z); VT[c4 + 3][rr] = f2bf(a * xv.w);
    }
    __syncthreads();

    f32x4 st[2];
    st[0] = (f32x4){0.f, 0.f, 0.f, 0.f};
    st[1] = (f32x4){0.f, 0.f, 0.f, 0.f};
#pragma unroll
    for (int kk = 0; kk < 64; kk += 32) {
        bf16x8 ak = *reinterpret_cast<const bf16x8*>(&KT[16 * mw + l15][kk + 8 * lq]);
#pragma unroll
        for (int i = 0; i < 2; ++i) {
            bf16x8 vb = *reinterpret_cast<const bf16x8*>(&VT[16 * (2 * nh + i) + l15][kk + 8 * lq]);
            st[i] = __builtin_amdgcn_mfma_f32_16x16x32_bf16(ak, vb, st[i], 0, 0, 0);
        }
    }
    float* o = dS0 + (size_t)(bh * 8 + j) * 4096;
#pragma unroll
    for (int i = 0; i < 2; ++i)
#pragma unroll
        for (int r = 0; r < 4; ++r)
            o[(16 * mw + 4 * lq + r) * 64 + 16 * (2 * nh + i) + l15] = st[i][r];
}

// ---------------------------------------------------------------------------
// out0_ds1 (512 threads, 8 waves): GLA output chunk + dS1 + EbT emission.
// ---------------------------------------------------------------------------
__global__ __launch_bounds__(512) void out0_ds1(const float* __restrict__ x,
                                                const ushort_t* __restrict__ xb,
                                                const ushort_t* __restrict__ Qb,
                                                const ushort_t* __restrict__ Kb,
                                                const ushort_t* __restrict__ K2b,
                                                const float* __restrict__ gc,
                                                const float* __restrict__ ab,
                                                const float* __restrict__ dS0,
                                                float* __restrict__ O1out,
                                                float* __restrict__ dS1,
                                                ushort_t* __restrict__ EbT) {
    const int rt = blockIdx.x, bh = blockIdx.y;
    const int b = bh >> 4, h = bh & 15;
    const int c0 = rt * 64;
    const int tid = threadIdx.x;
    const int w = tid >> 6, lane = tid & 63;
    const int l15 = lane & 15, lq = lane >> 4;
    const int tw = w >> 1, eh = w & 1;

    __shared__ __align__(16) char Qs[8192];
    __shared__ __align__(16) char Ks[8192];
    __shared__ ushort_t VT[64][72];
    __shared__ ushort_t K2T[64][72];
    __shared__ ushort_t ET[64][72];
    __shared__ ushort_t Ps[64][72];
    __shared__ ushort_t SBt[64][72];
    __shared__ float av[64], gcv[64];

    const size_t base = (size_t)(b * 512) * 1024 + h * 64;
    const size_t rowB = (size_t)(b * 512 + c0) * 2048 + h * 128;

    {
        const int p = tid * 16;
        const int row = p >> 7;
        const int scb = (p & 127) ^ ((row & 7) << 4);
        gl16((const char*)Qb + rowB + (size_t)row * 2048 + scb, Qs + w * 1024);
        gl16((const char*)Kb + rowB + (size_t)row * 2048 + scb, Ks + w * 1024);
    }
#pragma unroll
    for (int it = 0; it < 2; ++it) {
        const int idx = tid + it * 512;
        const int rr = idx >> 4;
        const int c4 = (idx & 15) << 2;
        const int tau = c0 + rr;
        ushort4 xv = *reinterpret_cast<const ushort4*>(xb + base + (size_t)tau * 1024 + c4);
        VT[c4 + 0][rr] = xv.x; VT[c4 + 1][rr] = xv.y;
        VT[c4 + 2][rr] = xv.z; VT[c4 + 3][rr] = xv.w;
        ushort4 cv = *reinterpret_cast<const ushort4*>(K2b + base + (size_t)tau * 1024 + c4);
        K2T[c4 + 0][rr] = cv.x; K2T[c4 + 1][rr] = cv.y;
        K2T[c4 + 2][rr] = cv.z; K2T[c4 + 3][rr] = cv.w;
    }
    if (tid < 64) av[tid] = ab[bh * 512 + c0 + tid];
    else if (tid < 128) gcv[tid - 64] = gc[bh * 512 + c0 + tid - 64];

#pragma unroll
    for (int ii = 0; ii < 2; ++ii) {
        const int flat = tid * 8 + ii * 4;
        float4 s = {0.f, 0.f, 0.f, 0.f};
        for (int jj = 0; jj < rt; ++jj) {
            float4 v = *reinterpret_cast<const float4*>(dS0 + (size_t)(bh * 8 + jj) * 4096 + flat);
            s.x += v.x; s.y += v.y; s.z += v.z; s.w += v.w;
        }
        const int d = flat >> 6, e = flat & 63;
        SBt[e + 0][d] = f2bf(s.x); SBt[e + 1][d] = f2bf(s.y);
        SBt[e + 2][d] = f2bf(s.z); SBt[e + 3][d] = f2bf(s.w);
    }
    __syncthreads();

    const int ra = 16 * tw + l15;
    f32x4 sc[2];
    sc[0] = (f32x4){0.f, 0.f, 0.f, 0.f};
    sc[1] = (f32x4){0.f, 0.f, 0.f, 0.f};
#pragma unroll
    for (int kk = 0; kk < 64; kk += 32) {
        const int cb = (kk + 8 * lq) * 2;
        bf16x8 aq = *reinterpret_cast<const bf16x8*>(Qs + ra * 128 + (cb ^ ((ra & 7) << 4)));
#pragma unroll
        for (int i = 0; i < 2; ++i) {
            const int rb = 16 * (2 * eh + i) + l15;
            bf16x8 bb = *reinterpret_cast<const bf16x8*>(Ks + rb * 128 + (cb ^ ((rb & 7) << 4)));
            sc[i] = __builtin_amdgcn_mfma_f32_16x16x32_bf16(aq, bb, sc[i], 0, 0, 0);
        }
    }
#pragma unroll
    for (int i = 0; i < 2; ++i) {
        const int cl = 16 * (2 * eh + i) + l15;
#pragma unroll
        for (int r = 0; r < 4; ++r) {
            const int tl = 16 * tw + 4 * lq + r;
            Ps[tl][cl] = f2bf(cl <= tl ? sc[i][r] * av[cl] : 0.f);
        }
    }
    __syncthreads();

    f32x4 oc[2];
    oc[0] = (f32x4){0.f, 0.f, 0.f, 0.f};
    oc[1] = (f32x4){0.f, 0.f, 0.f, 0.f};
#pragma unroll
    for (int kk = 0; kk < 64; kk += 32) {
        const int cb = (kk + 8 * lq) * 2;
        bf16x8 aq = *reinterpret_cast<const bf16x8*>(Qs + ra * 128 + (cb ^ ((ra & 7) << 4)));
        bf16x8 ap = *reinterpret_cast<const bf16x8*>(&Ps[16 * tw + l15][kk + 8 * lq]);
#pragma unroll
        for (int i = 0; i < 2; ++i) {
            const int nb = 16 * (2 * eh + i) + l15;
            bf16x8 sb = *reinterpret_cast<const bf16x8*>(&SBt[nb][kk + 8 * lq]);
            oc[i] = __builtin_amdgcn_mfma_f32_16x16x32_bf16(aq, sb, oc[i], 0, 0, 0);
            bf16x8 vb = *reinterpret_cast<const bf16x8*>(&VT[nb][kk + 8 * lq]);
            oc[i] = __builtin_amdgcn_mfma_f32_16x16x32_bf16(ap, vb, oc[i], 0, 0, 0);
        }
    }

#pragma unroll
    for (int i = 0; i < 2; ++i) {
        const int e = 16 * (2 * eh + i) + l15;
#pragma unroll
        for (int r = 0; r < 4; ++r) {
            const int tl = 16 * tw + 4 * lq + r;
            const int tau = c0 + tl;
            const float val = gcv[tl] * oc[i][r];
            O1out[base + (size_t)tau * 1024 + e] = val;
            float ev = 0.f;
            if (tau <= 510) ev = x[base + (size_t)(tau + 1) * 1024 + e] - val;
            ET[e][tl] = f2bf(ev);
        }
    }
    __syncthreads();

    {
        const int e = tid >> 3;
        const int tq = (tid & 7) * 8;
        uint4 v0 = *reinterpret_cast<const uint4*>(&ET[e][tq]);
        *reinterpret_cast<uint4*>(EbT + (size_t)(bh * 64 + e) * 512 + c0 + tq) = v0;
    }

    f32x4 st[2];
    st[0] = (f32x4){0.f, 0.f, 0.f, 0.f};
    st[1] = (f32x4){0.f, 0.f, 0.f, 0.f};
#pragma unroll
    for (int kk = 0; kk < 64; kk += 32) {
        bf16x8 ak = *reinterpret_cast<const bf16x8*>(&K2T[16 * tw + l15][kk + 8 * lq]);
#pragma unroll
        for (int i = 0; i < 2; ++i) {
            bf16x8 eb = *reinterpret_cast<const bf16x8*>(&ET[16 * (2 * eh + i) + l15][kk + 8 * lq]);
            st[i] = __builtin_amdgcn_mfma_f32_16x16x32_bf16(ak, eb, st[i], 0, 0, 0);
        }
    }
    float* o = dS1 + (size_t)(bh * 8 + rt) * 4096;
#pragma unroll
    for (int i = 0; i < 2; ++i)
#pragma unroll
        for (int r = 0; r < 4; ++r)
            o[(16 * tw + 4 * lq + r) * 64 + 16 * (2 * eh + i) + l15] = st[i][r];
}

// ---------------------------------------------------------------------------
// out1 (512 threads): MA-branch output + final y in bf16.
// ---------------------------------------------------------------------------
__global__ __launch_bounds__(512) void out1_k(const ushort_t* __restrict__ Q2b,
                                              const ushort_t* __restrict__ K2b,
                                              const ushort_t* __restrict__ EbT,
                                              const float* __restrict__ O1,
                                              const float* __restrict__ dS1,
                                              ushort_t* __restrict__ yout) {
    const int rt = blockIdx.x, bh = blockIdx.y;
    const int b = bh >> 4, h = bh & 15;
    const int c0 = rt * 64;
    const int tid = threadIdx.x;
    const int w = tid >> 6, lane = tid & 63;
    const int l15 = lane & 15, lq = lane >> 4;
    const int tw = w >> 1, eh = w & 1;

    __shared__ __align__(16) char Q2s[8192];
    __shared__ __align__(16) char K2s[8192];
    __shared__ __align__(16) char ETs[8192];
    __shared__ ushort_t Ps[64][72];
    __shared__ ushort_t SBt[64][72];

    const size_t base = (size_t)(b * 512) * 1024 + h * 64;
    const size_t rowB = (size_t)(b * 512 + c0) * 2048 + h * 128;

    {
        const int p = tid * 16;
        const int row = p >> 7;
        const int scb = (p & 127) ^ ((row & 7) << 4);
        gl16((const char*)Q2b + rowB + (size_t)row * 2048 + scb, Q2s + w * 1024);
        gl16((const char*)K2b + rowB + (size_t)row * 2048 + scb, K2s + w * 1024);
        gl16((const char*)EbT + (size_t)(bh * 64 + row) * 1024 + c0 * 2 + scb, ETs + w * 1024);
    }
#pragma unroll
    for (int ii = 0; ii < 2; ++ii) {
        const int flat = tid * 8 + ii * 4;
        float4 s = {0.f, 0.f, 0.f, 0.f};
        for (int jj = 0; jj < rt; ++jj) {
            float4 v = *reinterpret_cast<const float4*>(dS1 + (size_t)(bh * 8 + jj) * 4096 + flat);
            s.x += v.x; s.y += v.y; s.z += v.z; s.w += v.w;
        }
        const int d = flat >> 6, e = flat & 63;
        SBt[e + 0][d] = f2bf(s.x); SBt[e + 1][d] = f2bf(s.y);
        SBt[e + 2][d] = f2bf(s.z); SBt[e + 3][d] = f2bf(s.w);
    }
    __syncthreads();

    const int ra = 16 * tw + l15;
    f32x4 sc[2];
    sc[0] = (f32x4){0.f, 0.f, 0.f, 0.f};
    sc[1] = (f32x4){0.f, 0.f, 0.f, 0.f};
#pragma unroll
    for (int kk = 0; kk < 64; kk += 32) {
        const int cb = (kk + 8 * lq) * 2;
        bf16x8 aq = *reinterpret_cast<const bf16x8*>(Q2s + ra * 128 + (cb ^ ((ra & 7) << 4)));
#pragma unroll
        for (int i = 0; i < 2; ++i) {
            const int rb = 16 * (2 * eh + i) + l15;
            bf16x8 bb = *reinterpret_cast<const bf16x8*>(K2s + rb * 128 + (cb ^ ((rb & 7) << 4)));
            sc[i] = __builtin_amdgcn_mfma_f32_16x16x32_bf16(aq, bb, sc[i], 0, 0, 0);
        }
    }
#pragma unroll
    for (int i = 0; i < 2; ++i) {
        const int cl = 16 * (2 * eh + i) + l15;
#pragma unroll
        for (int r = 0; r < 4; ++r) {
            const int tl = 16 * tw + 4 * lq + r;
            Ps[tl][cl] = f2bf(cl <= tl ? sc[i][r] : 0.f);
        }
    }
    __syncthreads();

    f32x4 oc[2];
    oc[0] = (f32x4){0.f, 0.f, 0.f, 0.f};
    oc[1] = (f32x4){0.f, 0.f, 0.f, 0.f};
#pragma unroll
    for (int kk = 0; kk < 64; kk += 32) {
        const int cb = (kk + 8 * lq) * 2;
        bf16x8 aq = *reinterpret_cast<const bf16x8*>(Q2s + ra * 128 + (cb ^ ((ra & 7) << 4)));
        bf16x8 ap = *reinterpret_cast<const bf16x8*>(&Ps[16 * tw + l15][kk + 8 * lq]);
#pragma unroll
        for (int i = 0; i < 2; ++i) {
            const int rb = 16 * (2 * eh + i) + l15;
            bf16x8 sb = *reinterpret_cast<const bf16x8*>(&SBt[rb][kk + 8 * lq]);
            oc[i] = __builtin_amdgcn_mfma_f32_16x16x32_bf16(aq, sb, oc[i], 0, 0, 0);
            bf16x8 eb = *reinterpret_cast<const bf16x8*>(ETs + rb * 128 + (cb ^ ((rb & 7) << 4)));
            oc[i] = __builtin_amdgcn_mfma_f32_16x16x32_bf16(ap, eb, oc[i], 0, 0, 0);
        }
    }

#pragma unroll
    for (int i = 0; i < 2; ++i) {
        const int e = 16 * (2 * eh + i) + l15;
#pragma unroll
        for (int r = 0; r < 4; ++r) {
            const int tp = c0 + 16 * tw + 4 * lq + r;
            if (tp <= 510) {
                yout[(size_t)(b * 512 + tp + 1) * 1024 + h * 64 + e] =
                    f2bf(O1[base + (size_t)(tp + 1) * 1024 + e] + oc[i][r]);
            }
        }
    }
    if (rt == 0 && tid < 64)
        yout[(size_t)(b * 512) * 1024 + h * 64 + tid] = f2bf(O1[base + tid]);
}

// ---------------------------------------------------------------------------
// gemmP (512 threads): final projection, fp32 out, 3-deep counted-vmcnt.
// ---------------------------------------------------------------------------
__global__ __launch_bounds__(512) void gemmP(const ushort_t* __restrict__ Ab,
                                             const ushort_t* __restrict__ WT,
                                             const float* __restrict__ bias,
                                             float* __restrict__ Out) {
    const int m0 = blockIdx.y * 64, n0 = blockIdx.x * 64;
    __shared__ __align__(16) char smem[49152];   // As[3] @0, Bs[3] @24576

    const int tid = threadIdx.x;
    const int w = tid >> 6, lane = tid & 63;
    const int l15 = lane & 15, lq = lane >> 4;
    const int mw = w >> 1, nh = w & 1;

    f32x4 acc[2];
    acc[0] = (f32x4){0.f, 0.f, 0.f, 0.f};
    acc[1] = (f32x4){0.f, 0.f, 0.f, 0.f};

    auto stage = [&](int buf, int k0) {
        const int p = tid * 16;
        const int row = p >> 7;
        const int scb = (p & 127) ^ ((row & 7) << 4);
        gl16((const char*)Ab + (((size_t)(m0 + row)) << 11) + (k0 << 1) + scb,
             smem + buf * 8192 + w * 1024);
        gl16((const char*)WT + (((size_t)(n0 + row)) << 11) + (k0 << 1) + scb,
             smem + 24576 + buf * 8192 + w * 1024);
    };

    stage(0, 0);
    stage(1, 64);
#pragma unroll
    for (int it = 0; it < 16; ++it) {
        const int k0 = it * 64;
        const int cur = it % 3;
        if (it < 14) stage((it + 2) % 3, k0 + 128);
        if (it < 14)      asm volatile("s_waitcnt vmcnt(4)" ::: "memory");
        else if (it == 14) asm volatile("s_waitcnt vmcnt(2)" ::: "memory");
        else               asm volatile("s_waitcnt vmcnt(0)" ::: "memory");
        __builtin_amdgcn_sched_barrier(0);
        __builtin_amdgcn_s_barrier();
        const char* As = smem + cur * 8192;
        const char* Bs = smem + 24576 + cur * 8192;
#pragma unroll
        for (int kk = 0; kk < 64; kk += 32) {
            const int cb = (kk + 8 * lq) * 2;
            const int ra = 16 * mw + l15;
            bf16x8 a = *reinterpret_cast<const bf16x8*>(As + ra * 128 + (cb ^ ((ra & 7) << 4)));
#pragma unroll
            for (int i = 0; i < 2; ++i) {
                const int rb = 16 * (2 * nh + i) + l15;
                bf16x8 b = *reinterpret_cast<const bf16x8*>(Bs + rb * 128 + (cb ^ ((rb & 7) << 4)));
                acc[i] = __builtin_amdgcn_mfma_f32_16x16x32_bf16(a, b, acc[i], 0, 0, 0);
            }
        }
        asm volatile("s_waitcnt lgkmcnt(0)" ::: "memory");
        __builtin_amdgcn_sched_barrier(0);
        __builtin_amdgcn_s_barrier();
    }
#pragma unroll
    for (int i = 0; i < 2; ++i) {
        const int col = n0 + 16 * (2 * nh + i) + l15;
        const float bcol = bias[col];
#pragma unroll
        for (int r = 0; r < 4; ++r) {
            const int row = m0 + 16 * mw + 4 * lq + r;
            Out[(size_t)row * 1024 + col] = acc[i][r] + bcol;
        }
    }
}

// ---------------------------------------------------------------------------
extern "C" void kernel_launch(void* const* d_in, const int* in_sizes, int n_in,
                              void* d_out, int out_size, void* d_ws, size_t ws_size,
                              hipStream_t stream) {
    const float* x   = (const float*)d_in[0];
    const float* q1w = (const float*)d_in[1];
    const float* q1b = (const float*)d_in[2];
    const float* k1w = (const float*)d_in[3];
    const float* k1b = (const float*)d_in[4];
    const float* k2w = (const float*)d_in[5];
    const float* k2b = (const float*)d_in[6];
    const float* gww = (const float*)d_in[7];
    const float* gwb = (const float*)d_in[8];
    const float* sww = (const float*)d_in[9];
    const float* swb = (const float*)d_in[10];
    const float* cpw = (const float*)d_in[11];
    const float* cpb = (const float*)d_in[12];
    float* out = (float*)d_out;

    float* ws = (float*)d_ws;
    float* O1   = ws;                       // 1M floats
    float* dS0b = ws + 1048576;             // 1M
    float* dS1b = ws + 2097152;             // 1M
    float* gcb  = ws + 3145728;             // 16K
    float* abb  = ws + 3162112;             // 16K
    ushort_t* ub = (ushort_t*)(ws + 3178496);
    ushort_t* xb   = ub;                    // 1M ushorts each
    ushort_t* qb   = ub + 1048576;
    ushort_t* q2b  = ub + 2097152;
    ushort_t* kb   = ub + 3145728;
    ushort_t* k2q  = ub + 4194304;
    ushort_t* EbT  = ub + 5242880;
    ushort_t* wqT  = ub + 6291456;
    ushort_t* wkT  = ub + 7340032;
    ushort_t* wcT  = ub + 8388608;
    ushort_t* wpT  = ub + 9437184;
    ushort_t* ytb  = ub + 10485760;
    // end: ~35 MB of d_ws

    cvtT<<<1568, 256, 0, stream>>>(x, q1w, k1w, k2w, cpw, gww, gwb,
                                   xb, wqT, wkT, wcT, wpT, gcb);
    gemmQKC<<<dim3(16, 16, 3), 512, 0, stream>>>(xb, wqT, wkT, wcT, q1b, k1b, k2b,
                                                 x, sww, swb, gcb,
                                                 qb, q2b, kb, k2q, abb, dS0b);
    out0_ds1<<<dim3(8, 32), 512, 0, stream>>>(x, xb, qb, kb, k2q, gcb, abb, dS0b,
                                              O1, dS1b, EbT);
    out1_k<<<dim3(8, 32), 512, 0, stream>>>(q2b, k2q, EbT, O1, dS1b, ytb);
    gemmP<<<dim3(16, 16), 512, 0, stream>>>(ytb, wpT, cpb, out);
}